// Round 21
// baseline (151.026 us; speedup 1.0000x reference)
//
#include <hip/hip_runtime.h>
#include <cstddef>

// ----------------------------------------------------------------------------
// AttentionFusion round 21: r20 structure (4 kernels + counter-memset) with
// the hbuf dtype bug fixed: ffn1 epilogue writes BF16 (ffn2 consumes hbuf as
// raw bf16 MFMA operands; r20 wrote f16 bits there -> absmax 1.8).
//  K1 sxpypw(960): sx f16 rows + py_t f16 + PW_t bf16  [W1/Wf1 fp32 direct]
//  K2 scores(256): shared-panel 4wave/2row (proven 21us)
//  K3 ffn1(24,8):  K=896 split [speech | sum_n probs] x [Wf1_top | PW], bf16 out
//  K4 ffn2ln(108): outpre GEMM + last-blocks LayerNorm+time-mean
// ----------------------------------------------------------------------------

#define D_  768
#define NH_ 4
#define B_  4
#define T1_ 128
#define T2_ 128
#define M_  (B_*T1_)
#define LN_EPS_ 1e-5f
#define GEMM_SMEM 18944   // As 5120 + Bs 5120 + Ts 8704

typedef unsigned short u16;
typedef unsigned int u32;
typedef _Float16 f16;
typedef _Float16 f16x2 __attribute__((ext_vector_type(2)));
typedef __bf16 bf16x8 __attribute__((ext_vector_type(8)));
typedef float f32x4 __attribute__((ext_vector_type(4)));

__device__ __forceinline__ u16 f2bf(float f) {
    union { float f; unsigned int u; } v; v.f = f;
    unsigned int u = v.u + (0x7FFFu + ((v.u >> 16) & 1u));
    return (u16)(u >> 16);
}
__device__ __forceinline__ u32 pack_bf2(float lo, float hi) {
    return (u32)f2bf(lo) | ((u32)f2bf(hi) << 16);
}
__device__ __forceinline__ u16 f16bits(f16 h) {
    return __builtin_bit_cast(unsigned short, h);
}
__device__ __forceinline__ f16x2 bcast2(u32 u) {
    return __builtin_bit_cast(f16x2, u);
}
__device__ __forceinline__ u32 splat2(u16 h) { return (u32)h * 0x10001u; }

// ---------------- bf16 MFMA GEMM: C = A @ B + bias -------------------------
// AF32: A is f32 rows (bf16-converted during staging); else A is bf16 rows.
// BMODE: 0 = B pre-transposed bf16 [N][K]; 1 = B native fp32 [K][N]
//        (transpose folded into LDS staging; HW-proven in r7 mega-kernel).
// MODE: 0=f32 rows, 2=f16 rows, 3=f16 transposed, 4=bf16 transposed
template<bool RELU, int MODE, bool AF32, int BMODE>
__device__ __forceinline__ void gemm_mfma_body(
    const void* __restrict__ Av, int lda,
    const void* __restrict__ Bv, int ldb,
    const float* __restrict__ bias,
    void* __restrict__ C, int ldc, int K, int m0, int n0, char* smem)
{
    u16 (*As)[40] = reinterpret_cast<u16(*)[40]>(smem);           // 5120 B
    u16 (*Bs)[40] = reinterpret_cast<u16(*)[40]>(smem + 5120);    // 5120 B
    u16 (*Ts)[68] = reinterpret_cast<u16(*)[68]>(smem + 10240);   // 8704 B

    const int tid = threadIdx.x;
    const int row = tid >> 2;
    const int kq  = (tid & 3) << 3;
    const int kp  = tid >> 4;          // BMODE=1: k-pair 0..15
    const int nq  = (tid & 15) << 2;   // BMODE=1: n quad 0..60
    const int lane = tid & 63;
    const int w  = tid >> 6;
    const int wr = (w >> 1) << 5;
    const int wc = (w & 1) << 5;
    const int l16 = lane & 15;
    const int lk8 = (lane >> 4) << 3;
    const int r4  = (lane >> 4) << 2;

    const u16*   aptr16 = (const u16*)Av + (size_t)(m0 + row) * lda + kq;
    const float* aptrf  = (const float*)Av + (size_t)(m0 + row) * lda + kq;
    const u16*   bptr16 = (const u16*)Bv + (size_t)(n0 + row) * ldb + kq;
    const float* bptrf  = (const float*)Bv + (size_t)(2 * kp) * ldb + n0 + nq;

    f32x4 acc00 = {0.f,0.f,0.f,0.f}, acc01 = {0.f,0.f,0.f,0.f};
    f32x4 acc10 = {0.f,0.f,0.f,0.f}, acc11 = {0.f,0.f,0.f,0.f};

    uint4 a_nxt; uint4 bu; float4 bx, by;
    auto loadA = [&](int k0) -> uint4 {
        if (AF32) {
            float4 ax = *(const float4*)(aptrf + k0);
            float4 ay = *(const float4*)(aptrf + k0 + 4);
            uint4 r;
            r.x = pack_bf2(ax.x, ax.y); r.y = pack_bf2(ax.z, ax.w);
            r.z = pack_bf2(ay.x, ay.y); r.w = pack_bf2(ay.z, ay.w);
            return r;
        }
        return *(const uint4*)(aptr16 + k0);
    };
    auto loadB = [&](int k0) {
        if (BMODE == 1) {
            bx = *(const float4*)(bptrf + (size_t)k0 * ldb);
            by = *(const float4*)(bptrf + (size_t)(k0 + 1) * ldb);
        } else {
            bu = *(const uint4*)(bptr16 + k0);
        }
    };

    a_nxt = loadA(0); loadB(0);

    for (int k0 = 0; k0 < K; k0 += 32) {
        __syncthreads();
        *(uint4*)&As[row][kq] = a_nxt;
        if (BMODE == 1) {
            *(u32*)&Bs[nq + 0][2 * kp] = pack_bf2(bx.x, by.x);
            *(u32*)&Bs[nq + 1][2 * kp] = pack_bf2(bx.y, by.y);
            *(u32*)&Bs[nq + 2][2 * kp] = pack_bf2(bx.z, by.z);
            *(u32*)&Bs[nq + 3][2 * kp] = pack_bf2(bx.w, by.w);
        } else {
            *(uint4*)&Bs[row][kq] = bu;
        }
        if (k0 + 32 < K) { a_nxt = loadA(k0 + 32); loadB(k0 + 32); }
        __syncthreads();
        bf16x8 af0 = *(const bf16x8*)&As[wr + l16][lk8];
        bf16x8 af1 = *(const bf16x8*)&As[wr + 16 + l16][lk8];
        bf16x8 bf0 = *(const bf16x8*)&Bs[wc + l16][lk8];
        bf16x8 bf1 = *(const bf16x8*)&Bs[wc + 16 + l16][lk8];
        acc00 = __builtin_amdgcn_mfma_f32_16x16x32_bf16(af0, bf0, acc00, 0, 0, 0);
        acc01 = __builtin_amdgcn_mfma_f32_16x16x32_bf16(af0, bf1, acc01, 0, 0, 0);
        acc10 = __builtin_amdgcn_mfma_f32_16x16x32_bf16(af1, bf0, acc10, 0, 0, 0);
        acc11 = __builtin_amdgcn_mfma_f32_16x16x32_bf16(af1, bf1, acc11, 0, 0, 0);
    }

#define EPI_FRAG(ACC, MF, NF)                                                  \
    {                                                                          \
        const int gcol = n0 + wc + (NF)*16 + l16;                              \
        const float bv = bias ? bias[gcol] : 0.f;                              \
        float v_[4];                                                           \
        _Pragma("unroll")                                                      \
        for (int r = 0; r < 4; r++) {                                          \
            float v = ACC[r] + bv;                                             \
            if (RELU) v = fmaxf(v, 0.f);                                       \
            v_[r] = v;                                                         \
        }                                                                      \
        const int lr0 = wr + (MF)*16 + r4;                                     \
        if (MODE >= 3) {                                                       \
            const int lc = wc + (NF)*16 + l16;                                 \
            _Pragma("unroll")                                                  \
            for (int r = 0; r < 4; r++)                                        \
                Ts[lc][lr0 + r] = (MODE == 3) ? f16bits((f16)v_[r])            \
                                              : f2bf(v_[r]);                   \
        } else {                                                               \
            _Pragma("unroll")                                                  \
            for (int r = 0; r < 4; r++) {                                      \
                const size_t off = (size_t)(m0 + lr0 + r) * ldc + gcol;        \
                if (MODE == 0) ((float*)C)[off] = v_[r];                       \
                else ((u16*)C)[off] = f16bits((f16)v_[r]);                     \
            }                                                                  \
        }                                                                      \
    }
    EPI_FRAG(acc00, 0, 0) EPI_FRAG(acc01, 0, 1)
    EPI_FRAG(acc10, 1, 0) EPI_FRAG(acc11, 1, 1)
#undef EPI_FRAG

    if (MODE >= 3) {
        // coalesced write of the 64(m->s) x 64(n->h) tile into C[h][128]
        __syncthreads();
        u16* cb = (u16*)C + (size_t)(m0 >> 7) * ((size_t)ldc * 128) + (m0 & 127);
#pragma unroll
        for (int u = 0; u < 4; u++) {
            const int i = tid + u * 256;
            const int hl = i >> 4;
            const int s4 = (i & 15) << 2;
            ushort4 o;
            o.x = Ts[hl][s4 + 0]; o.y = Ts[hl][s4 + 1];
            o.z = Ts[hl][s4 + 2]; o.w = Ts[hl][s4 + 3];
            *(ushort4*)(cb + (size_t)(n0 + hl) * 128 + s4) = o;
        }
    }
}

// ---------------------------------------------------------------------------
// K1: sx + py_t + PW_t batched, weights fp32 direct. 1D grid 960.
// ---------------------------------------------------------------------------
__global__ __launch_bounds__(256) void sxpypw_kernel(
    const float* __restrict__ sp, const float* __restrict__ ph,
    const float* __restrict__ W1, const float* __restrict__ Wf1,
    const float* __restrict__ b1,
    u16* __restrict__ sxf, u16* __restrict__ pyt, u16* __restrict__ pwt)
{
    __shared__ __align__(16) char smem[GEMM_SMEM];
    int job = blockIdx.x;
    if (job < 384) {
        const int n = job / 96, r = job % 96, my = r / 12, nx = r % 12;
        gemm_mfma_body<false, 2, true, 1>(sp, 768,
            W1 + (size_t)n * 1536 * 768, 768, b1 + n * 768,
            sxf + (size_t)n * M_ * 768, 768, 768, my * 64, nx * 64, smem);
    } else if (job < 768) {
        const int j = job - 384;
        const int n = j / 96, r = j % 96, my = r / 12, nx = r % 12;
        gemm_mfma_body<false, 3, true, 1>(ph, 768,
            W1 + (size_t)n * 1536 * 768 + (size_t)768 * 768, 768, nullptr,
            pyt + (size_t)n * 4 * 768 * 128, 768, 768, my * 64, nx * 64, smem);
    } else {
        const int j = job - 768;
        const int b = j / 48, r = j % 48, my = r / 24, nx = r % 24;
        gemm_mfma_body<false, 4, true, 1>(ph + (size_t)b * 128 * 768, 768,
            Wf1 + (size_t)768 * 1536, 1536, nullptr,
            pwt + (size_t)b * 1536 * 128, 1536, 768, my * 64, nx * 64, smem);
    }
}

// ---------------------------------------------------------------------------
// K2: scores + softmax — PROVEN r2/r16 geometry: block=(n,b,t8), 4 waves
// lockstep on ONE py panel (L1 sharing), each wave 2 t-rows. 0.25-scaled.
// ---------------------------------------------------------------------------
__global__ __launch_bounds__(256) void scores_softmax_kernel(
    const u16* __restrict__ sxf,     // f16 [n][512][768]
    const u16* __restrict__ pyt,     // f16 [n][b][768][128]
    const float* __restrict__ w2,    // f32 [n][768]
    float* __restrict__ probs)       // f32 [n][512][128]
{
    const int bid = blockIdx.x;
    const int n = bid >> 6, b = (bid >> 4) & 3, t0 = (bid & 15) * 8;
    const int tid = threadIdx.x, lane = tid & 63, w = tid >> 6;

    __shared__ __align__(16) f16x2 sxs[8][768];
    __shared__ __align__(16) f16x2 w2s[768];

    for (int q = 0; q < 6; q++) {
        const int u = tid + q * 256;
        const int r = u / 192;
        const int h4 = (u % 192) * 4;
        ushort4 v = *(const ushort4*)(sxf + ((size_t)(n * 512 + b * 128 + t0 + r)) * 768 + h4);
        sxs[r][h4 + 0] = bcast2(splat2(v.x));
        sxs[r][h4 + 1] = bcast2(splat2(v.y));
        sxs[r][h4 + 2] = bcast2(splat2(v.z));
        sxs[r][h4 + 3] = bcast2(splat2(v.w));
    }
    for (int q = 0; q < 3; q++) {
        const int i = tid + q * 256;
        w2s[i] = bcast2(splat2(f16bits((f16)w2[n * 768 + i])));
    }
    __syncthreads();

    const f16x2* pypanel = (const f16x2*)(pyt + ((size_t)((n << 2) | b)) * 768 * 128) + lane;
    const f16x2 z2 = {(f16)0, (f16)0};

    float accA0 = 0.f, accA1 = 0.f, accB0 = 0.f, accB1 = 0.f;
    const int rA = 2 * w, rB = 2 * w + 1;

    f16x2 b0[16], b1[16];
#pragma unroll
    for (int j = 0; j < 16; j++) b0[j] = pypanel[(size_t)j * 64];
#pragma unroll
    for (int j = 0; j < 16; j++) b1[j] = pypanel[(size_t)(16 + j) * 64];

    auto compute = [&](const f16x2 (&buf)[16], int hbase) {
        f16x2 aA = z2, aB = z2;
#pragma unroll
        for (int j4 = 0; j4 < 16; j4 += 4) {
            uint4 sau = *(const uint4*)&sxs[rA][hbase + j4];
            uint4 sbu = *(const uint4*)&sxs[rB][hbase + j4];
            uint4 wvu = *(const uint4*)&w2s[hbase + j4];
            const u32 sa_[4] = {sau.x, sau.y, sau.z, sau.w};
            const u32 sb_[4] = {sbu.x, sbu.y, sbu.z, sbu.w};
            const u32 wv_[4] = {wvu.x, wvu.y, wvu.z, wvu.w};
#pragma unroll
            for (int j = 0; j < 4; j++) {
                const f16x2 pv = buf[j4 + j];
                const f16x2 wj = bcast2(wv_[j]);
                f16x2 ra = __builtin_elementwise_max(bcast2(sa_[j]) + pv, z2);
                f16x2 rb = __builtin_elementwise_max(bcast2(sb_[j]) + pv, z2);
                aA = __builtin_elementwise_fma(ra, wj, aA);
                aB = __builtin_elementwise_fma(rb, wj, aB);
            }
        }
        accA0 += (float)aA.x; accA1 += (float)aA.y;
        accB0 += (float)aB.x; accB1 += (float)aB.y;
    };

    for (int hc = 0; hc < 768; hc += 32) {
        compute(b0, hc);
        if (hc + 32 < 768) {
#pragma unroll
            for (int j = 0; j < 16; j++) b0[j] = pypanel[(size_t)(hc + 32 + j) * 64];
        }
        compute(b1, hc + 16);
        if (hc + 48 < 768) {
#pragma unroll
            for (int j = 0; j < 16; j++) b1[j] = pypanel[(size_t)(hc + 48 + j) * 64];
        }
    }

#pragma unroll
    for (int which = 0; which < 2; which++) {
        const float s0 = which ? accB0 : accA0;
        const float s1 = which ? accB1 : accA1;
        const int t = t0 + 2 * w + which;
        float mx = fmaxf(s0, s1);
#pragma unroll
        for (int off = 32; off; off >>= 1) mx = fmaxf(mx, __shfl_xor(mx, off, 64));
        const float e0 = expf(s0 - mx), e1 = expf(s1 - mx);
        float sm = e0 + e1;
#pragma unroll
        for (int off = 32; off; off >>= 1) sm += __shfl_xor(sm, off, 64);
        const float inv = 0.25f / sm;
        float2 pr; pr.x = e0 * inv; pr.y = e1 * inv;
        *(float2*)&probs[((size_t)(n * 512 + b * 128 + t)) * 128 + 2 * lane] = pr;
    }
}

// ---------------------------------------------------------------------------
// K3: FFN1' : hbuf(BF16) = relu(speech @ Wf1_top + attn @ PW[b] + bf1), K=896.
// ---------------------------------------------------------------------------
__global__ __launch_bounds__(256) void gemm_ffn1_kernel(
    const float* __restrict__ speech, const float* __restrict__ probs,
    const float* __restrict__ Wf1, const u16* __restrict__ pwt,
    const float* __restrict__ bf1, u16* __restrict__ hbuf)
{
    __shared__ __align__(16) u16 As[64][40];
    __shared__ __align__(16) u16 Bs[64][40];

    const int tid = threadIdx.x;
    const int row = tid >> 2;
    const int kq  = (tid & 3) << 3;
    const int kp  = tid >> 4;
    const int nq  = (tid & 15) << 2;
    const int lane = tid & 63;
    const int w  = tid >> 6;
    const int wr = (w >> 1) << 5;
    const int wc = (w & 1) << 5;
    const int l16 = lane & 15;
    const int lk8 = (lane >> 4) << 3;
    const int r4  = (lane >> 4) << 2;

    const int m0 = blockIdx.y * 64, n0 = blockIdx.x * 64;
    const int b = m0 >> 7;

    const float* arow = speech + (size_t)(m0 + row) * 768 + kq;
    const float* prow = probs + (size_t)(m0 + row) * 128 + kq;
    const float* bptrf = Wf1 + (size_t)(2 * kp) * 1536 + n0 + nq;
    const u16* brow_p = pwt + (size_t)b * 1536 * 128 + (size_t)(n0 + row) * 128 + kq;

    f32x4 acc00 = {0.f,0.f,0.f,0.f}, acc01 = {0.f,0.f,0.f,0.f};
    f32x4 acc10 = {0.f,0.f,0.f,0.f}, acc11 = {0.f,0.f,0.f,0.f};

    uint4 a_nxt; uint4 bu; float4 bx, by;
    auto loadA = [&](int k0) -> uint4 {
        uint4 r;
        if (k0 < 768) {
            float4 ax = *(const float4*)(arow + k0);
            float4 ay = *(const float4*)(arow + k0 + 4);
            r.x = pack_bf2(ax.x, ax.y); r.y = pack_bf2(ax.z, ax.w);
            r.z = pack_bf2(ay.x, ay.y); r.w = pack_bf2(ay.z, ay.w);
        } else {
            const int ko = k0 - 768;
            float4 ax = make_float4(0.f, 0.f, 0.f, 0.f), ay = ax;
#pragma unroll
            for (int n = 0; n < 4; n++) {
                float4 u0 = *(const float4*)(prow + (size_t)n * 512 * 128 + ko);
                float4 u1 = *(const float4*)(prow + (size_t)n * 512 * 128 + ko + 4);
                ax.x += u0.x; ax.y += u0.y; ax.z += u0.z; ax.w += u0.w;
                ay.x += u1.x; ay.y += u1.y; ay.z += u1.z; ay.w += u1.w;
            }
            r.x = pack_bf2(ax.x, ax.y); r.y = pack_bf2(ax.z, ax.w);
            r.z = pack_bf2(ay.x, ay.y); r.w = pack_bf2(ay.z, ay.w);
        }
        return r;
    };
    auto loadB = [&](int k0) {
        if (k0 < 768) {
            bx = *(const float4*)(bptrf + (size_t)k0 * 1536);
            by = *(const float4*)(bptrf + (size_t)(k0 + 1) * 1536);
        } else {
            bu = *(const uint4*)(brow_p + (k0 - 768));
        }
    };

    a_nxt = loadA(0); loadB(0);

    for (int k0 = 0; k0 < 896; k0 += 32) {
        __syncthreads();
        *(uint4*)&As[row][kq] = a_nxt;
        if (k0 < 768) {
            *(u32*)&Bs[nq + 0][2 * kp] = pack_bf2(bx.x, by.x);
            *(u32*)&Bs[nq + 1][2 * kp] = pack_bf2(bx.y, by.y);
            *(u32*)&Bs[nq + 2][2 * kp] = pack_bf2(bx.z, by.z);
            *(u32*)&Bs[nq + 3][2 * kp] = pack_bf2(bx.w, by.w);
        } else {
            *(uint4*)&Bs[row][kq] = bu;
        }
        if (k0 + 32 < 896) { a_nxt = loadA(k0 + 32); loadB(k0 + 32); }
        __syncthreads();
        bf16x8 af0 = *(const bf16x8*)&As[wr + l16][lk8];
        bf16x8 af1 = *(const bf16x8*)&As[wr + 16 + l16][lk8];
        bf16x8 bf0 = *(const bf16x8*)&Bs[wc + l16][lk8];
        bf16x8 bf1 = *(const bf16x8*)&Bs[wc + 16 + l16][lk8];
        acc00 = __builtin_amdgcn_mfma_f32_16x16x32_bf16(af0, bf0, acc00, 0, 0, 0);
        acc01 = __builtin_amdgcn_mfma_f32_16x16x32_bf16(af0, bf1, acc01, 0, 0, 0);
        acc10 = __builtin_amdgcn_mfma_f32_16x16x32_bf16(af1, bf0, acc10, 0, 0, 0);
        acc11 = __builtin_amdgcn_mfma_f32_16x16x32_bf16(af1, bf1, acc11, 0, 0, 0);
    }

#define EPI_FFN1(ACC, MF, NF)                                                  \
    {                                                                          \
        const int gcol = n0 + wc + (NF)*16 + l16;                              \
        const float bv = bf1[gcol];                                            \
        const int lr0 = wr + (MF)*16 + r4;                                     \
        _Pragma("unroll")                                                      \
        for (int r = 0; r < 4; r++) {                                          \
            float v = fmaxf(ACC[r] + bv, 0.f);                                 \
            hbuf[(size_t)(m0 + lr0 + r) * 1536 + gcol] = f2bf(v);  /* BF16! */ \
        }                                                                      \
    }
    EPI_FFN1(acc00, 0, 0) EPI_FFN1(acc01, 0, 1)
    EPI_FFN1(acc10, 1, 0) EPI_FFN1(acc11, 1, 1)
#undef EPI_FFN1
}

// ---------------------------------------------------------------------------
// K4: ffn2 + LN fused. grid 108 = 96 GEMM blocks + 12 LN blocks.
// ---------------------------------------------------------------------------
__global__ __launch_bounds__(256) void ffn2_ln_kernel(
    const u16* __restrict__ hbuf, const float* __restrict__ Wf2,
    const float* __restrict__ bf2, const float* __restrict__ g,
    const float* __restrict__ lb, float* __restrict__ outpre,
    float* __restrict__ out, unsigned int* __restrict__ cnt)
{
    __shared__ __align__(16) char smem[GEMM_SMEM];
    const int bid = blockIdx.x;
    const int tid = threadIdx.x;

    if (bid < 96) {
        const int my = bid / 12, nx = bid % 12;
        gemm_mfma_body<false, 0, false, 1>(hbuf, 1536, Wf2, 768, bf2,
                                           outpre, 768, 1536,
                                           my * 64, nx * 64, smem);
        __threadfence();
        __syncthreads();
        if (tid == 0)
            __hip_atomic_fetch_add(cnt, 1u, __ATOMIC_RELEASE, __HIP_MEMORY_SCOPE_AGENT);
        return;
    }

    // LN blocks: wait for all GEMM blocks, then LN + time-mean.
    if (tid == 0) {
        while (__hip_atomic_load(cnt, __ATOMIC_ACQUIRE, __HIP_MEMORY_SCOPE_AGENT) < 96u)
            __builtin_amdgcn_s_sleep(8);
    }
    __syncthreads();
    __threadfence();

    const int j = bid - 96;
    const int b = j / 3, c = j % 3;
    const int lane = tid & 63, w = tid >> 6;
    float* rs = reinterpret_cast<float*>(smem);        // 128 floats
    float* Sred = rs + 128;                            // 4 floats

    float prsum = 0.f;
    for (int i = 0; i < 32; i++) {
        const int rowg = w * 32 + i;
        const float4* x4 = (const float4*)(outpre + ((size_t)(b * T1_ + rowg)) * D_);
        float s = 0.f, ss = 0.f;
#pragma unroll
        for (int jj = 0; jj < 3; jj++) {
            float4 v = x4[jj * 64 + lane];
            s += v.x + v.y + v.z + v.w;
            ss += v.x * v.x + v.y * v.y + v.z * v.z + v.w * v.w;
        }
#pragma unroll
        for (int off = 32; off; off >>= 1) {
            s += __shfl_xor(s, off, 64);
            ss += __shfl_xor(ss, off, 64);
        }
        if (lane == 0) {
            const float mu = s * (1.f / D_);
            const float var = ss * (1.f / D_) - mu * mu;
            const float r = rsqrtf(var + LN_EPS_);
            rs[rowg] = r;
            prsum += mu * r;
        }
    }
    if (lane == 0) Sred[w] = prsum;
    __syncthreads();
    const float S = Sred[0] + Sred[1] + Sred[2] + Sred[3];
    const float* xb = outpre + (size_t)b * T1_ * D_;
    const int d = c * 256 + tid;
    float acc = 0.f;
#pragma unroll 8
    for (int t = 0; t < T1_; t++)
        acc = fmaf(xb[(size_t)t * D_ + d], rs[t], acc);
    out[b * D_ + d] = g[d] * (acc - S) * (1.f / T1_) + lb[d];
}

extern "C" void kernel_launch(void* const* d_in, const int* in_sizes, int n_in,
                              void* d_out, int out_size, void* d_ws, size_t ws_size,
                              hipStream_t stream)
{
    const float* speech = (const float*)d_in[0];
    const float* phon   = (const float*)d_in[1];
    const float* W1     = (const float*)d_in[2];
    const float* b1     = (const float*)d_in[3];
    const float* w2     = (const float*)d_in[4];
    // d_in[5] = b2: softmax-invariant, unused
    const float* Wf1    = (const float*)d_in[6];
    const float* bf1    = (const float*)d_in[7];
    const float* Wf2    = (const float*)d_in[8];
    const float* bf2    = (const float*)d_in[9];
    const float* ln_g   = (const float*)d_in[10];
    const float* ln_b   = (const float*)d_in[11];
    float* out = (float*)d_out;

    char* w = (char*)d_ws;
    auto alloc = [&](size_t bytes) { char* p = w; w += (bytes + 1023) & ~(size_t)1023; return p; };
    u16* sxf    = (u16*)alloc((size_t)NH_ * M_ * 768 * 2);        // f16
    u16* pyt    = (u16*)alloc((size_t)NH_ * B_ * 768 * 128 * 2);  // f16 transposed
    u16* pwt    = (u16*)alloc((size_t)B_ * 1536 * 128 * 2);       // bf16 transposed
    float* probs  = (float*)alloc((size_t)NH_ * M_ * T2_ * 4);
    u16* hbuf   = (u16*)alloc((size_t)M_ * 2 * 768 * 2);          // bf16
    float* outpre = (float*)alloc((size_t)M_ * D_ * 4);
    unsigned int* cnt = (unsigned int*)alloc(64);

    hipMemsetAsync(cnt, 0, 4, stream);
    hipLaunchKernelGGL(sxpypw_kernel, dim3(960), dim3(256), 0, stream,
                       speech, phon, W1, Wf1, b1, sxf, pyt, pwt);
    hipLaunchKernelGGL(scores_softmax_kernel, dim3(256), dim3(256), 0, stream,
                       sxf, pyt, w2, probs);
    hipLaunchKernelGGL(gemm_ffn1_kernel, dim3(24, 8), dim3(256), 0, stream,
                       speech, probs, Wf1, pwt, bf1, hbuf);
    hipLaunchKernelGGL(ffn2_ln_kernel, dim3(108), dim3(256), 0, stream,
                       hbuf, Wf2, bf2, ln_g, ln_b, outpre, out, cnt);
}